// Round 2
// baseline (462.579 us; speedup 1.0000x reference)
//
#include <hip/hip_runtime.h>
#include <math.h>

#define S_ 2048
#define R_ 384

typedef __attribute__((ext_vector_type(8))) short bf16x8;
typedef __attribute__((ext_vector_type(4))) float f32x4;

static __device__ __forceinline__ f32x4 mfma16(bf16x8 a, bf16x8 b, f32x4 c) {
  return __builtin_amdgcn_mfma_f32_16x16x32_bf16(a, b, c, 0, 0, 0);
}

// fp32 -> bf16 round-to-nearest-even
static __device__ __forceinline__ unsigned short f2bf(float f) {
  unsigned u = __float_as_uint(f);
  u += 0x7fffu + ((u >> 16) & 1u);
  return (unsigned short)(u >> 16);
}
static __device__ __forceinline__ float bf2f(unsigned short s) {
  return __uint_as_float(((unsigned)s) << 16);
}
static __device__ __forceinline__ float bflo(unsigned u) {
  return __uint_as_float(u << 16);
}
static __device__ __forceinline__ float bfhi(unsigned u) {
  return __uint_as_float(u & 0xffff0000u);
}

static __device__ __forceinline__ bf16x8 pack8(float4 a, float4 b) {
  bf16x8 r;
  unsigned short* p = (unsigned short*)&r;
  p[0] = f2bf(a.x); p[1] = f2bf(a.y); p[2] = f2bf(a.z); p[3] = f2bf(a.w);
  p[4] = f2bf(b.x); p[5] = f2bf(b.y); p[6] = f2bf(b.z); p[7] = f2bf(b.w);
  return r;
}

// ---- Kernel 1: raw-x MFMA + epilogue-LN; K/V + gate + g2(frag layout) + q ----
// grid (8, R), block 256 (4 waves). Block covers 256 s-rows of column r.
// kv bf16 [r][s][16]. g2 bf16 fragment-ordered: per 16-row tile 2KB =
// frag0(64 lanes x 16B) | frag1, tile index = r*128 + chunk*16 + it*4 + w.
__global__ __launch_bounds__(256) void k_lnkv(
    const float* __restrict__ m, const float* __restrict__ lnw_g,
    const float* __restrict__ lnb_g, const float* __restrict__ Wk,
    const float* __restrict__ Wv, const float* __restrict__ Wg,
    const float* __restrict__ bg, unsigned short* __restrict__ kv,
    float* __restrict__ qpart, unsigned short* __restrict__ g2) {
  __shared__ unsigned short xt[4][16 * 72];  // per-wave gate tile, pad 72
  __shared__ float qred[4][64];
  __shared__ float qmured[4];

  const int t = threadIdx.x;
  const int w = t >> 6, l = t & 63;
  const int lane_n = l & 15, quad = l >> 4;
  const int r = blockIdx.y, chunk = blockIdx.x;
  const int c8 = quad * 8;

  // ---- weight frags with lnw folded in; column sums + lnb-dot biases ----
  bf16x8 bkv[2], Bg[4][2];
  float csKV = 0.f, lbKV = 0.f;
  float csG[4] = {0.f, 0.f, 0.f, 0.f}, lbG[4] = {0.f, 0.f, 0.f, 0.f};
#pragma unroll
  for (int kk = 0; kk < 2; ++kk) {
#pragma unroll
    for (int j = 0; j < 8; ++j) {
      const int k = kk * 32 + quad * 8 + j;
      const float lw = lnw_g[k], lb = lnb_g[k];
      const float w0 = (lane_n < 8) ? Wk[k * 8 + lane_n] : Wv[k * 8 + lane_n - 8];
      unsigned short bb = f2bf(lw * w0);
      ((unsigned short*)&bkv[kk])[j] = bb;
      float bf = bf2f(bb);
      csKV += bf;
      lbKV = fmaf(lb, bf, lbKV);
#pragma unroll
      for (int n = 0; n < 4; ++n) {
        bb = f2bf(lw * Wg[k * 64 + n * 16 + lane_n]);
        ((unsigned short*)&Bg[n][kk])[j] = bb;
        bf = bf2f(bb);
        csG[n] += bf;
        lbG[n] = fmaf(lb, bf, lbG[n]);
      }
    }
  }
#pragma unroll
  for (int msk = 16; msk <= 32; msk <<= 1) {
    csKV += __shfl_xor(csKV, msk);
    lbKV += __shfl_xor(lbKV, msk);
#pragma unroll
    for (int n = 0; n < 4; ++n) {
      csG[n] += __shfl_xor(csG[n], msk);
      lbG[n] += __shfl_xor(lbG[n], msk);
    }
  }
  float gb[4];
#pragma unroll
  for (int n = 0; n < 4; ++n) gb[n] = lbG[n] + bg[n * 16 + lane_n];

  // direct fragment loads from m: lane = (row lane_n, c = c8..c8+7 / +32)
  const float* mp =
      m + ((size_t)(chunk * 256 + w * 16 + lane_n) * R_ + r) * 64 + c8;
  const size_t itstep = (size_t)64 * R_ * 64;

  float4 xa = *(const float4*)(mp + 0);
  float4 xb = *(const float4*)(mp + 4);
  float4 xc = *(const float4*)(mp + 32);
  float4 xd = *(const float4*)(mp + 36);

  float4 qa = make_float4(0.f, 0.f, 0.f, 0.f), qb = qa, qc = qa, qd = qa;
  float qmu = 0.f;
  unsigned short* xw = xt[w];

#pragma unroll
  for (int it = 0; it < 4; ++it) {
    float4 na, nb, nc, nd;
    if (it < 3) {
      const float* np = mp + (size_t)(it + 1) * itstep;
      na = *(const float4*)(np + 0);
      nb = *(const float4*)(np + 4);
      nc = *(const float4*)(np + 32);
      nd = *(const float4*)(np + 36);
    }
    // pack raw x -> A-frags (MFMA input does NOT wait on LN stats)
    const bf16x8 a0 = pack8(xa, xb);
    const bf16x8 a1 = pack8(xc, xd);

    // LN stats for row lane_n (16 elems/lane, reduce across quads)
    float s1 = ((xa.x + xa.y) + (xa.z + xa.w)) + ((xb.x + xb.y) + (xb.z + xb.w)) +
               ((xc.x + xc.y) + (xc.z + xc.w)) + ((xd.x + xd.y) + (xd.z + xd.w));
    float s2 = xa.x * xa.x;
    s2 = fmaf(xa.y, xa.y, s2); s2 = fmaf(xa.z, xa.z, s2); s2 = fmaf(xa.w, xa.w, s2);
    s2 = fmaf(xb.x, xb.x, s2); s2 = fmaf(xb.y, xb.y, s2); s2 = fmaf(xb.z, xb.z, s2);
    s2 = fmaf(xb.w, xb.w, s2);
    s2 = fmaf(xc.x, xc.x, s2); s2 = fmaf(xc.y, xc.y, s2); s2 = fmaf(xc.z, xc.z, s2);
    s2 = fmaf(xc.w, xc.w, s2);
    s2 = fmaf(xd.x, xd.x, s2); s2 = fmaf(xd.y, xd.y, s2); s2 = fmaf(xd.z, xd.z, s2);
    s2 = fmaf(xd.w, xd.w, s2);
    s1 += __shfl_xor(s1, 16); s1 += __shfl_xor(s1, 32);
    s2 += __shfl_xor(s2, 16); s2 += __shfl_xor(s2, 32);
    const float mu = s1 * (1.f / 64.f);
    const float var = fmaf(-mu, mu, s2 * (1.f / 64.f));
    const float inv = rsqrtf(var + 1e-5f);

    // q-pool partials (off critical path)
    qa.x = fmaf(inv, xa.x, qa.x); qa.y = fmaf(inv, xa.y, qa.y);
    qa.z = fmaf(inv, xa.z, qa.z); qa.w = fmaf(inv, xa.w, qa.w);
    qb.x = fmaf(inv, xb.x, qb.x); qb.y = fmaf(inv, xb.y, qb.y);
    qb.z = fmaf(inv, xb.z, qb.z); qb.w = fmaf(inv, xb.w, qb.w);
    qc.x = fmaf(inv, xc.x, qc.x); qc.y = fmaf(inv, xc.y, qc.y);
    qc.z = fmaf(inv, xc.z, qc.z); qc.w = fmaf(inv, xc.w, qc.w);
    qd.x = fmaf(inv, xd.x, qd.x); qd.y = fmaf(inv, xd.y, qd.y);
    qd.z = fmaf(inv, xd.z, qd.z); qd.w = fmaf(inv, xd.w, qd.w);
    qmu = fmaf(inv, mu, qmu);

    // MFMA on raw x
    f32x4 acc = {0.f, 0.f, 0.f, 0.f};
    acc = mfma16(a0, bkv[0], acc);
    acc = mfma16(a1, bkv[1], acc);
    f32x4 gacc[4];
#pragma unroll
    for (int n = 0; n < 4; ++n) {
      f32x4 z = {0.f, 0.f, 0.f, 0.f};
      z = mfma16(a0, Bg[n][0], z);
      gacc[n] = mfma16(a1, Bg[n][1], z);
    }

    // redistribute stats: epilogue lane needs rows quad*4+rg (owner lane = row)
    float inv_e[4], mu_e[4];
#pragma unroll
    for (int rg = 0; rg < 4; ++rg) {
      inv_e[rg] = __shfl(inv, quad * 4 + rg);
      mu_e[rg]  = __shfl(mu,  quad * 4 + rg);
    }

    const int s0 = chunk * 256 + it * 64 + w * 16;
    // kv epilogue: y = inv*(acc - mu*cs) + lb
#pragma unroll
    for (int rg = 0; rg < 4; ++rg) {
      const float y = fmaf(inv_e[rg], acc[rg] - mu_e[rg] * csKV, lbKV);
      kv[((size_t)r * S_ + s0 + quad * 4 + rg) * 16 + lane_n] = f2bf(y);
    }
    // gate epilogue: sigmoid(inv*(gacc - mu*cs) + (lnb.Wg + bg)) -> LDS tile
#pragma unroll
    for (int n = 0; n < 4; ++n) {
#pragma unroll
      for (int rg = 0; rg < 4; ++rg) {
        const float gp = fmaf(inv_e[rg], gacc[n][rg] - mu_e[rg] * csG[n], gb[n]);
        const float gv = 1.f / (1.f + __expf(-gp));
        xw[(quad * 4 + rg) * 72 + n * 16 + lane_n] = f2bf(gv);
      }
    }
    __builtin_amdgcn_wave_barrier();
    // read frags from tile, store g2 contiguous (1KB per wave instruction)
    const bf16x8 g0 = *(const bf16x8*)(xw + lane_n * 72 + c8);
    const bf16x8 g1 = *(const bf16x8*)(xw + lane_n * 72 + 32 + c8);
    unsigned short* gp2 =
        g2 + ((size_t)(r * 128 + chunk * 16 + it * 4 + w)) * 1024;
    *(bf16x8*)(gp2 + l * 8) = g0;
    *(bf16x8*)(gp2 + 512 + l * 8) = g1;
    __builtin_amdgcn_wave_barrier();

    if (it < 3) { xa = na; xb = nb; xc = nc; xd = nd; }
  }

  // reduce q partials across rows (lane_n bits)
#pragma unroll
  for (int msk = 1; msk <= 8; msk <<= 1) {
    qa.x += __shfl_xor(qa.x, msk); qa.y += __shfl_xor(qa.y, msk);
    qa.z += __shfl_xor(qa.z, msk); qa.w += __shfl_xor(qa.w, msk);
    qb.x += __shfl_xor(qb.x, msk); qb.y += __shfl_xor(qb.y, msk);
    qb.z += __shfl_xor(qb.z, msk); qb.w += __shfl_xor(qb.w, msk);
    qc.x += __shfl_xor(qc.x, msk); qc.y += __shfl_xor(qc.y, msk);
    qc.z += __shfl_xor(qc.z, msk); qc.w += __shfl_xor(qc.w, msk);
    qd.x += __shfl_xor(qd.x, msk); qd.y += __shfl_xor(qd.y, msk);
    qd.z += __shfl_xor(qd.z, msk); qd.w += __shfl_xor(qd.w, msk);
  }
#pragma unroll
  for (int msk = 1; msk <= 32; msk <<= 1) qmu += __shfl_xor(qmu, msk);
  if (lane_n == 0) {
    *(float4*)(&qred[w][c8])      = qa;
    *(float4*)(&qred[w][c8 + 4])  = qb;
    *(float4*)(&qred[w][32 + c8])     = qc;
    *(float4*)(&qred[w][32 + c8 + 4]) = qd;
    if (quad == 0) qmured[w] = qmu * 0.25f;  // each row counted by 4 lanes
  }
  __syncthreads();
  if (t < 64) {
    const float Sx = qred[0][t] + qred[1][t] + qred[2][t] + qred[3][t];
    const float Smu = qmured[0] + qmured[1] + qmured[2] + qmured[3];
    qpart[((size_t)chunk * R_ + r) * 64 + t] =
        lnw_g[t] * (Sx - Smu) + 256.f * lnb_g[t];
  }
}

// ---- Kernel 2: pooled q + chunked partial softmax ----
// grid (8, R), block 256. apart[r][chunk][h]: {m, l, ov[8]} (10 floats)
__global__ __launch_bounds__(256) void k_attn(
    const float* __restrict__ qpart, const float* __restrict__ Wq,
    const unsigned short* __restrict__ kv, float* __restrict__ apart) {
  __shared__ float qs[64];
  __shared__ float q[64];
  __shared__ float mred[8 * 32];
  __shared__ float mhs[8];
  __shared__ float lred[8 * 32];
  __shared__ float opart[32 * 64];

  const int t = threadIdx.x;
  const int chunk = blockIdx.x, r = blockIdx.y;

  if (t < 64) {
    float s = 0.f;
#pragma unroll
    for (int ch = 0; ch < 8; ++ch) s += qpart[((size_t)ch * R_ + r) * 64 + t];
    qs[t] = s * (1.f / 2048.f);   // /(S+1e-10) rounds to /2048 in fp32
  }
  __syncthreads();
  if (t < 64) {
    float acc = 0.f;
    for (int c = 0; c < 64; ++c) acc = fmaf(qs[c], Wq[c * 64 + t], acc);
    q[t] = acc * 0.35355339059327373f;   // Ch^-0.5
  }
  __syncthreads();

  const int h = t & 7, part = t >> 3;   // 32 parts x 8 s-rows each
  float qh[8];
#pragma unroll
  for (int j = 0; j < 8; ++j) qh[j] = q[h * 8 + j];

  const int sbase = chunk * 256 + part * 8;
  float d[8];
#pragma unroll
  for (int j = 0; j < 8; ++j) {
    const unsigned short* kp = kv + ((size_t)r * S_ + sbase + j) * 16;
    const uint4 kr = *(const uint4*)kp;
    float dd;
    dd = qh[0] * bflo(kr.x) + qh[1] * bfhi(kr.x);
    dd = fmaf(qh[2], bflo(kr.y), fmaf(qh[3], bfhi(kr.y), dd));
    dd = fmaf(qh[4], bflo(kr.z), fmaf(qh[5], bfhi(kr.z), dd));
    dd = fmaf(qh[6], bflo(kr.w), fmaf(qh[7], bfhi(kr.w), dd));
    d[j] = dd;
  }
  float mx = -1e30f;
#pragma unroll
  for (int j = 0; j < 8; ++j) mx = fmaxf(mx, d[j]);
  mred[h * 32 + part] = mx;
  __syncthreads();
  if (t < 8) {
    float mh_ = -1e30f;
    for (int p = 0; p < 32; ++p) mh_ = fmaxf(mh_, mred[t * 32 + p]);
    mhs[t] = mh_;
  }
  __syncthreads();
  const float mh = mhs[h];

  float l_acc = 0.f;
  float av[8];
#pragma unroll
  for (int j = 0; j < 8; ++j) av[j] = 0.f;
#pragma unroll
  for (int j = 0; j < 8; ++j) {
    const unsigned short* kp = kv + ((size_t)r * S_ + sbase + j) * 16;
    const uint4 vr = *(const uint4*)(kp + 8);
    const float e = __expf(d[j] - mh);
    l_acc += e;
    av[0] = fmaf(e, bflo(vr.x), av[0]); av[1] = fmaf(e, bfhi(vr.x), av[1]);
    av[2] = fmaf(e, bflo(vr.y), av[2]); av[3] = fmaf(e, bfhi(vr.y), av[3]);
    av[4] = fmaf(e, bflo(vr.z), av[4]); av[5] = fmaf(e, bfhi(vr.z), av[5]);
    av[6] = fmaf(e, bflo(vr.w), av[6]); av[7] = fmaf(e, bfhi(vr.w), av[7]);
  }
  lred[h * 32 + part] = l_acc;
#pragma unroll
  for (int j = 0; j < 8; ++j) opart[part * 64 + h * 8 + j] = av[j];
  __syncthreads();

  if (t < 64) {
    const int hh = t >> 3, jj = t & 7;
    float L = 0.f;
    for (int p = 0; p < 32; ++p) L += lred[hh * 32 + p];
    float O = 0.f;
    for (int p = 0; p < 32; ++p) O += opart[p * 64 + t];
    float* ap = apart + (((size_t)r * 8 + chunk) * 8 + hh) * 10;
    if (jj == 0) { ap[0] = mhs[hh]; ap[1] = L; }
    ap[2 + jj] = O;
  }
}

// ---- Kernel 3: attn combine + output GEMM, no LDS tiles, no barriers ----
// grid (8, R), block 256 (4 waves). Swapped MFMA: D = (o.*Wo)^T . g^T so the
// output lane layout stores as float4 directly. g read as coalesced frags.
__global__ __launch_bounds__(256) void k_out(
    const unsigned short* __restrict__ g2, const float* __restrict__ apart,
    const float* __restrict__ Wo, const float* __restrict__ bo,
    float* __restrict__ out) {
  __shared__ float osm[64];

  const int t = threadIdx.x;
  const int w = t >> 6, l = t & 63;
  const int lane_n = l & 15, quad = l >> 4;
  const int r = blockIdx.y, chunk = blockIdx.x;

  // exact combine of 8 chunk-partials: o[h*8+j]
  if (t < 64) {
    const int h = t >> 3, j = t & 7;
    float M = -1e30f;
#pragma unroll
    for (int c = 0; c < 8; ++c)
      M = fmaxf(M, apart[(((size_t)r * 8 + c) * 8 + h) * 10]);
    float L = 0.f, O = 0.f;
#pragma unroll
    for (int c = 0; c < 8; ++c) {
      const float* ap = apart + (((size_t)r * 8 + c) * 8 + h) * 10;
      const float wgt = __expf(ap[0] - M);
      L = fmaf(ap[1], wgt, L);
      O = fmaf(ap[2 + j], wgt, O);
    }
    osm[t] = O / L;
  }
  __syncthreads();

  // A-operand frags: A[c][hc] = osm[hc]*Wo[hc][c], c = n*16 + lane_n
  bf16x8 Ao[4][2];
  float4 bo4[4];
#pragma unroll
  for (int n = 0; n < 4; ++n) {
    bo4[n] = *(const float4*)(bo + n * 16 + quad * 4);
#pragma unroll
    for (int kk = 0; kk < 2; ++kk) {
#pragma unroll
      for (int j = 0; j < 8; ++j) {
        const int k = kk * 32 + quad * 8 + j;
        ((unsigned short*)&Ao[n][kk])[j] =
            f2bf(osm[k] * Wo[k * 64 + n * 16 + lane_n]);
      }
    }
  }

  const unsigned short* gbase =
      g2 + ((size_t)(r * 128 + chunk * 16 + w)) * 1024;
  bf16x8 gf0 = *(const bf16x8*)(gbase + l * 8);
  bf16x8 gf1 = *(const bf16x8*)(gbase + 512 + l * 8);

#pragma unroll
  for (int it = 0; it < 4; ++it) {
    bf16x8 n0, n1;
    if (it < 3) {
      const unsigned short* gn = gbase + (size_t)(it + 1) * 4096;
      n0 = *(const bf16x8*)(gn + l * 8);
      n1 = *(const bf16x8*)(gn + 512 + l * 8);
    }
    f32x4 oacc[4];
#pragma unroll
    for (int n = 0; n < 4; ++n) {
      f32x4 z = {0.f, 0.f, 0.f, 0.f};
      z = mfma16(Ao[n][0], gf0, z);
      oacc[n] = mfma16(Ao[n][1], gf1, z);
    }
    const int s0 = chunk * 256 + it * 64 + w * 16;
    float* op = out + ((size_t)(s0 + lane_n) * R_ + r) * 64 + quad * 4;
#pragma unroll
    for (int n = 0; n < 4; ++n) {
      float4 ov;
      ov.x = oacc[n][0] + bo4[n].x;
      ov.y = oacc[n][1] + bo4[n].y;
      ov.z = oacc[n][2] + bo4[n].z;
      ov.w = oacc[n][3] + bo4[n].w;
      *(float4*)(op + n * 16) = ov;
    }
    if (it < 3) { gf0 = n0; gf1 = n1; }
  }
}

extern "C" void kernel_launch(void* const* d_in, const int* in_sizes, int n_in,
                              void* d_out, int out_size, void* d_ws, size_t ws_size,
                              hipStream_t stream) {
  (void)in_sizes; (void)n_in; (void)out_size; (void)ws_size;
  const float* m   = (const float*)d_in[0];
  const float* lnw = (const float*)d_in[1];
  const float* lnb = (const float*)d_in[2];
  const float* Wq  = (const float*)d_in[3];
  const float* Wk  = (const float*)d_in[4];
  const float* Wv  = (const float*)d_in[5];
  const float* Wg  = (const float*)d_in[6];
  const float* bg  = (const float*)d_in[7];
  const float* Wo  = (const float*)d_in[8];
  const float* bo  = (const float*)d_in[9];
  float* out = (float*)d_out;

  // ws layout: kv bf16 [R*S*16] | qpart f32 [8*R*64] | apart f32 [R*8*8*10]
  //          | g2 bf16 frag-ordered [R*128 tiles * 1024]          (~128 MB)
  unsigned short* kv = (unsigned short*)d_ws;
  float* qpart = (float*)((char*)d_ws + (size_t)R_ * S_ * 16 * 2);
  float* apart = qpart + (size_t)8 * R_ * 64;
  unsigned short* g2 = (unsigned short*)(apart + (size_t)R_ * 8 * 8 * 10);

  k_lnkv<<<dim3(8, R_), 256, 0, stream>>>(m, lnw, lnb, Wk, Wv, Wg, bg, kv, qpart, g2);
  k_attn<<<dim3(8, R_), 256, 0, stream>>>(qpart, Wq, kv, apart);
  k_out<<<dim3(8, R_), 256, 0, stream>>>(g2, apart, Wo, bo, out);
}

// Round 3
// 433.873 us; speedup vs baseline: 1.0662x; 1.0662x over previous
//
#include <hip/hip_runtime.h>
#include <math.h>

#define S_ 2048
#define R_ 384

typedef __attribute__((ext_vector_type(8))) short bf16x8;
typedef __attribute__((ext_vector_type(4))) float f32x4;

static __device__ __forceinline__ f32x4 mfma16(bf16x8 a, bf16x8 b, f32x4 c) {
  return __builtin_amdgcn_mfma_f32_16x16x32_bf16(a, b, c, 0, 0, 0);
}

// fp32 -> bf16 round-to-nearest-even
static __device__ __forceinline__ unsigned short f2bf(float f) {
  unsigned u = __float_as_uint(f);
  u += 0x7fffu + ((u >> 16) & 1u);
  return (unsigned short)(u >> 16);
}
static __device__ __forceinline__ float bflo(unsigned u) {
  return __uint_as_float(u << 16);
}
static __device__ __forceinline__ float bfhi(unsigned u) {
  return __uint_as_float(u & 0xffff0000u);
}

// LayerNorm of one 64-float row spread across a 16-lane group (lane holds 4
// consecutive c at c4). Wave-synchronous shfl reduction within the group.
__device__ __forceinline__ float4 ln_quad(const float4 x4, const float* lnw,
                                          const float* lnb, int c4) {
  float s1 = x4.x + x4.y + x4.z + x4.w;
  float s2 = fmaf(x4.x, x4.x, fmaf(x4.y, x4.y, fmaf(x4.z, x4.z, x4.w * x4.w)));
#pragma unroll
  for (int msk = 1; msk <= 8; msk <<= 1) {
    s1 += __shfl_xor(s1, msk);
    s2 += __shfl_xor(s2, msk);
  }
  float mu  = s1 * (1.f / 64.f);
  float var = fmaf(-mu, mu, s2 * (1.f / 64.f));
  float inv = rsqrtf(var + 1e-5f);
  float nb  = -mu * inv;
  float4 xl;
  xl.x = fmaf(fmaf(x4.x, inv, nb), lnw[c4 + 0], lnb[c4 + 0]);
  xl.y = fmaf(fmaf(x4.y, inv, nb), lnw[c4 + 1], lnb[c4 + 1]);
  xl.z = fmaf(fmaf(x4.z, inv, nb), lnw[c4 + 2], lnb[c4 + 2]);
  xl.w = fmaf(fmaf(x4.w, inv, nb), lnw[c4 + 3], lnb[c4 + 3]);
  return xl;
}

// ---- Kernel 1: LN + K/V GEMM + gate GEMM + sigmoid + g2(frag) + q partials ----
// grid (8, R), block 256 (4 waves). Block covers 256 s-rows of column r.
// kv bf16 [r][s][16]. g2 bf16 fragment-ordered: per 16-row tile 2KB =
// frag0(64 lanes x 16B) | frag1, tile index = r*128 + chunk*16 + it*4 + w.
__global__ __launch_bounds__(256) void k_lnkv(
    const float* __restrict__ m, const float* __restrict__ lnw_g,
    const float* __restrict__ lnb_g, const float* __restrict__ Wk,
    const float* __restrict__ Wv, const float* __restrict__ Wg,
    const float* __restrict__ bg, unsigned short* __restrict__ kv,
    float* __restrict__ qpart, unsigned short* __restrict__ g2) {
  __shared__ unsigned short xt[4][16 * 72];  // per-wave bf16 tile, pad 72
  __shared__ float lnw[64], lnb[64];
  __shared__ float qred[4][64];

  const int t = threadIdx.x;
  const int w = t >> 6, l = t & 63;
  const int lane_n = l & 15, quad = l >> 4;
  const int r = blockIdx.y, chunk = blockIdx.x;

  if (t < 64) { lnw[t] = lnw_g[t]; lnb[t] = lnb_g[t]; }

  // B-frags in registers: [Wk|Wv] (N=16) and Wg (N=64), K=64 -> 2 frags each.
  bf16x8 bkv[2];
  bf16x8 Bg[4][2];
  float bgv[4];
#pragma unroll
  for (int kk = 0; kk < 2; ++kk) {
#pragma unroll
    for (int j = 0; j < 8; ++j) {
      const int k = kk * 32 + quad * 8 + j;
      const float wv_ = (lane_n < 8) ? Wk[k * 8 + lane_n] : Wv[k * 8 + lane_n - 8];
      ((unsigned short*)&bkv[kk])[j] = f2bf(wv_);
    }
  }
#pragma unroll
  for (int n = 0; n < 4; ++n) {
    bgv[n] = bg[n * 16 + lane_n];
#pragma unroll
    for (int kk = 0; kk < 2; ++kk) {
#pragma unroll
      for (int j = 0; j < 8; ++j) {
        const int k = kk * 32 + quad * 8 + j;
        ((unsigned short*)&Bg[n][kk])[j] = f2bf(Wg[k * 64 + n * 16 + lane_n]);
      }
    }
  }
  __syncthreads();

  unsigned short* xw = xt[w];
  const int c4 = lane_n * 4;
  float4 qacc = make_float4(0.f, 0.f, 0.f, 0.f);

  for (int it = 0; it < 4; ++it) {
    const int s0 = chunk * 256 + it * 64 + w * 16;
#pragma unroll
    for (int p = 0; p < 4; ++p) {
      const int row = p * 4 + quad;
      const float4 x4 = *(const float4*)(m + ((size_t)(s0 + row) * R_ + r) * 64 + c4);
      const float4 xl = ln_quad(x4, lnw, lnb, c4);
      qacc.x += xl.x; qacc.y += xl.y; qacc.z += xl.z; qacc.w += xl.w;
      ushort4 pk;
      pk.x = f2bf(xl.x); pk.y = f2bf(xl.y); pk.z = f2bf(xl.z); pk.w = f2bf(xl.w);
      *(ushort4*)(xw + row * 72 + c4) = pk;
    }
    __builtin_amdgcn_wave_barrier();
    const bf16x8 a0 = *(const bf16x8*)(xw + lane_n * 72 + quad * 8);
    const bf16x8 a1 = *(const bf16x8*)(xw + lane_n * 72 + 32 + quad * 8);
    // K/V projection
    f32x4 acc = {0.f, 0.f, 0.f, 0.f};
    acc = mfma16(a0, bkv[0], acc);
    acc = mfma16(a1, bkv[1], acc);
    // gate GEMM
    f32x4 gacc[4];
#pragma unroll
    for (int n = 0; n < 4; ++n) {
      f32x4 z = {0.f, 0.f, 0.f, 0.f};
      z = mfma16(a0, Bg[n][0], z);
      gacc[n] = mfma16(a1, Bg[n][1], z);
    }
#pragma unroll
    for (int rg = 0; rg < 4; ++rg)
      kv[((size_t)r * S_ + s0 + quad * 4 + rg) * 16 + lane_n] = f2bf(acc[rg]);
    __builtin_amdgcn_wave_barrier();
    // sigmoid gate -> bf16 -> LDS tile row-major [s][hc]
#pragma unroll
    for (int n = 0; n < 4; ++n) {
#pragma unroll
      for (int reg = 0; reg < 4; ++reg) {
        const float gv = 1.f / (1.f + __expf(-(gacc[n][reg] + bgv[n])));
        xw[(quad * 4 + reg) * 72 + n * 16 + lane_n] = f2bf(gv);
      }
    }
    __builtin_amdgcn_wave_barrier();
    // read back as MFMA B-frags, store g2 contiguous (1KB per wave instruction)
    const bf16x8 g0 = *(const bf16x8*)(xw + lane_n * 72 + quad * 8);
    const bf16x8 g1 = *(const bf16x8*)(xw + lane_n * 72 + 32 + quad * 8);
    unsigned short* gp2 =
        g2 + ((size_t)(r * 128 + chunk * 16 + it * 4 + w)) * 1024;
    *(bf16x8*)(gp2 + l * 8) = g0;
    *(bf16x8*)(gp2 + 512 + l * 8) = g1;
    __builtin_amdgcn_wave_barrier();
  }

  // reduce q partials across row slots (lane bits 4,5)
#pragma unroll
  for (int msk = 16; msk <= 32; msk <<= 1) {
    qacc.x += __shfl_xor(qacc.x, msk);
    qacc.y += __shfl_xor(qacc.y, msk);
    qacc.z += __shfl_xor(qacc.z, msk);
    qacc.w += __shfl_xor(qacc.w, msk);
  }
  if (l < 16) *(float4*)(&qred[w][c4]) = qacc;
  __syncthreads();
  if (t < 64)
    qpart[((size_t)chunk * R_ + r) * 64 + t] =
        qred[0][t] + qred[1][t] + qred[2][t] + qred[3][t];
}

// ---- Kernel 1b: pooled q (once per r) ----
// grid (R), block 64.
__global__ __launch_bounds__(64) void k_q(
    const float* __restrict__ qpart, const float* __restrict__ Wq,
    float* __restrict__ q_ws) {
  __shared__ float qs[64];
  const int t = threadIdx.x, r = blockIdx.x;
  float s = 0.f;
#pragma unroll
  for (int ch = 0; ch < 8; ++ch) s += qpart[((size_t)ch * R_ + r) * 64 + t];
  qs[t] = s * (1.f / 2048.f);   // /(S+1e-10) rounds to /2048 in fp32
  __syncthreads();
  float acc = 0.f;
  for (int c = 0; c < 64; ++c) acc = fmaf(qs[c], Wq[c * 64 + t], acc);
  q_ws[(size_t)r * 64 + t] = acc * 0.35355339059327373f;   // Ch^-0.5
}

// ---- Kernel 2: chunked partial softmax ----
// grid (8, R), block 256. apart[r][chunk][h]: {m, l, ov[8]} (10 floats)
__global__ __launch_bounds__(256) void k_attn(
    const float* __restrict__ q_ws, const unsigned short* __restrict__ kv,
    float* __restrict__ apart) {
  __shared__ float mred[8 * 32];
  __shared__ float mhs[8];
  __shared__ float lred[8 * 32];
  __shared__ float opart[32 * 64];

  const int t = threadIdx.x;
  const int chunk = blockIdx.x, r = blockIdx.y;
  const int h = t & 7, part = t >> 3;   // 32 parts x 8 s-rows each

  float qh[8];
#pragma unroll
  for (int j = 0; j < 8; ++j) qh[j] = q_ws[(size_t)r * 64 + h * 8 + j];

  const int sbase = chunk * 256 + part * 8;
  float d[8];
#pragma unroll
  for (int j = 0; j < 8; ++j) {
    const unsigned short* kp = kv + ((size_t)r * S_ + sbase + j) * 16;
    const uint4 kr = *(const uint4*)kp;
    float dd;
    dd = qh[0] * bflo(kr.x) + qh[1] * bfhi(kr.x);
    dd = fmaf(qh[2], bflo(kr.y), fmaf(qh[3], bfhi(kr.y), dd));
    dd = fmaf(qh[4], bflo(kr.z), fmaf(qh[5], bfhi(kr.z), dd));
    dd = fmaf(qh[6], bflo(kr.w), fmaf(qh[7], bfhi(kr.w), dd));
    d[j] = dd;
  }
  float mx = -1e30f;
#pragma unroll
  for (int j = 0; j < 8; ++j) mx = fmaxf(mx, d[j]);
  mred[h * 32 + part] = mx;
  __syncthreads();
  if (t < 8) {
    float mh_ = -1e30f;
    for (int p = 0; p < 32; ++p) mh_ = fmaxf(mh_, mred[t * 32 + p]);
    mhs[t] = mh_;
  }
  __syncthreads();
  const float mh = mhs[h];

  float l_acc = 0.f;
  float av[8];
#pragma unroll
  for (int j = 0; j < 8; ++j) av[j] = 0.f;
#pragma unroll
  for (int j = 0; j < 8; ++j) {
    const unsigned short* kp = kv + ((size_t)r * S_ + sbase + j) * 16;
    const uint4 vr = *(const uint4*)(kp + 8);
    const float e = __expf(d[j] - mh);
    l_acc += e;
    av[0] = fmaf(e, bflo(vr.x), av[0]); av[1] = fmaf(e, bfhi(vr.x), av[1]);
    av[2] = fmaf(e, bflo(vr.y), av[2]); av[3] = fmaf(e, bfhi(vr.y), av[3]);
    av[4] = fmaf(e, bflo(vr.z), av[4]); av[5] = fmaf(e, bfhi(vr.z), av[5]);
    av[6] = fmaf(e, bflo(vr.w), av[6]); av[7] = fmaf(e, bfhi(vr.w), av[7]);
  }
  lred[h * 32 + part] = l_acc;
#pragma unroll
  for (int j = 0; j < 8; ++j) opart[part * 64 + h * 8 + j] = av[j];
  __syncthreads();

  if (t < 64) {
    const int hh = t >> 3, jj = t & 7;
    float L = 0.f;
    for (int p = 0; p < 32; ++p) L += lred[hh * 32 + p];
    float O = 0.f;
    for (int p = 0; p < 32; ++p) O += opart[p * 64 + t];
    float* ap = apart + (((size_t)r * 8 + chunk) * 8 + hh) * 10;
    if (jj == 0) { ap[0] = mhs[hh]; ap[1] = L; }
    ap[2 + jj] = O;
  }
}

// ---- Kernel 2b: exact combine of chunk partials (once per r) ----
// grid (R), block 64. osm_ws[r][h*8+j].
__global__ __launch_bounds__(64) void k_comb(
    const float* __restrict__ apart, float* __restrict__ osm_ws) {
  const int t = threadIdx.x, r = blockIdx.x;
  const int h = t >> 3, j = t & 7;
  float M = -1e30f;
#pragma unroll
  for (int c = 0; c < 8; ++c)
    M = fmaxf(M, apart[(((size_t)r * 8 + c) * 8 + h) * 10]);
  float L = 0.f, O = 0.f;
#pragma unroll
  for (int c = 0; c < 8; ++c) {
    const float* ap = apart + (((size_t)r * 8 + c) * 8 + h) * 10;
    const float wgt = __expf(ap[0] - M);
    L = fmaf(ap[1], wgt, L);
    O = fmaf(ap[2 + j], wgt, O);
  }
  osm_ws[(size_t)r * 64 + t] = O / L;
}

// ---- Kernel 3: output GEMM. Frag g2 register loads, swapped MFMA,
// LDS-transposed 256B-coalesced stores. grid (8, R), block 256 (4 waves).
__global__ __launch_bounds__(256) void k_out(
    const unsigned short* __restrict__ g2, const float* __restrict__ osm_ws,
    const float* __restrict__ Wo, const float* __restrict__ bo,
    float* __restrict__ out) {
  __shared__ float osm[64];
  __shared__ __align__(16) float ot[4][16 * 68];  // per-wave f32 out tile

  const int t = threadIdx.x;
  const int w = t >> 6, l = t & 63;
  const int lane_n = l & 15, quad = l >> 4;
  const int r = blockIdx.y, chunk = blockIdx.x;

  if (t < 64) osm[t] = osm_ws[(size_t)r * 64 + t];
  __syncthreads();

  // A-operand frags: A[c][hc] = osm[hc]*Wo[hc][c], c = n*16 + lane_n
  bf16x8 Ao[4][2];
  float4 bo4[4];
#pragma unroll
  for (int n = 0; n < 4; ++n) {
    bo4[n] = *(const float4*)(bo + n * 16 + quad * 4);
#pragma unroll
    for (int kk = 0; kk < 2; ++kk) {
#pragma unroll
      for (int j = 0; j < 8; ++j) {
        const int k = kk * 32 + quad * 8 + j;
        ((unsigned short*)&Ao[n][kk])[j] =
            f2bf(osm[k] * Wo[k * 64 + n * 16 + lane_n]);
      }
    }
  }

  const unsigned short* gbase =
      g2 + ((size_t)(r * 128 + chunk * 16 + w)) * 1024;
  bf16x8 gf0 = *(const bf16x8*)(gbase + l * 8);
  bf16x8 gf1 = *(const bf16x8*)(gbase + 512 + l * 8);
  float* ow = ot[w];

#pragma unroll
  for (int it = 0; it < 4; ++it) {
    bf16x8 n0, n1;
    if (it < 3) {
      const unsigned short* gn = gbase + (size_t)(it + 1) * 4096;
      n0 = *(const bf16x8*)(gn + l * 8);
      n1 = *(const bf16x8*)(gn + 512 + l * 8);
    }
    f32x4 oacc[4];
#pragma unroll
    for (int n = 0; n < 4; ++n) {
      f32x4 z = {0.f, 0.f, 0.f, 0.f};
      z = mfma16(Ao[n][0], gf0, z);
      oacc[n] = mfma16(Ao[n][1], gf1, z);
    }
    // lane holds D[c = n*16+quad*4+reg][s = lane_n]; transpose via LDS
#pragma unroll
    for (int n = 0; n < 4; ++n) {
      float4 ov;
      ov.x = oacc[n][0] + bo4[n].x;
      ov.y = oacc[n][1] + bo4[n].y;
      ov.z = oacc[n][2] + bo4[n].z;
      ov.w = oacc[n][3] + bo4[n].w;
      *(float4*)(ow + lane_n * 68 + n * 16 + quad * 4) = ov;
    }
    __builtin_amdgcn_wave_barrier();
    const int s0 = chunk * 256 + it * 64 + w * 16;
#pragma unroll
    for (int pp = 0; pp < 4; ++pp) {
      const int row = pp * 4 + (l >> 4), cc = (l & 15) * 4;
      const float4 ov = *(const float4*)(ow + row * 68 + cc);
      *(float4*)(out + ((size_t)(s0 + row) * R_ + r) * 64 + cc) = ov;
    }
    __builtin_amdgcn_wave_barrier();
    if (it < 3) { gf0 = n0; gf1 = n1; }
  }
}

extern "C" void kernel_launch(void* const* d_in, const int* in_sizes, int n_in,
                              void* d_out, int out_size, void* d_ws, size_t ws_size,
                              hipStream_t stream) {
  (void)in_sizes; (void)n_in; (void)out_size; (void)ws_size;
  const float* m   = (const float*)d_in[0];
  const float* lnw = (const float*)d_in[1];
  const float* lnb = (const float*)d_in[2];
  const float* Wq  = (const float*)d_in[3];
  const float* Wk  = (const float*)d_in[4];
  const float* Wv  = (const float*)d_in[5];
  const float* Wg  = (const float*)d_in[6];
  const float* bg  = (const float*)d_in[7];
  const float* Wo  = (const float*)d_in[8];
  const float* bo  = (const float*)d_in[9];
  float* out = (float*)d_out;

  // ws: kv bf16 [R*S*16] | qpart f32 [8*R*64] | apart f32 [R*8*8*10]
  //   | q f32 [R*64] | osm f32 [R*64] | g2 bf16 frag-ordered [R*128*1024]
  unsigned short* kv = (unsigned short*)d_ws;
  float* qpart  = (float*)((char*)d_ws + (size_t)R_ * S_ * 16 * 2);
  float* apart  = qpart + (size_t)8 * R_ * 64;
  float* q_ws   = apart + (size_t)R_ * 8 * 8 * 10;
  float* osm_ws = q_ws + (size_t)R_ * 64;
  unsigned short* g2 = (unsigned short*)(osm_ws + (size_t)R_ * 64);

  k_lnkv<<<dim3(8, R_), 256, 0, stream>>>(m, lnw, lnb, Wk, Wv, Wg, bg, kv, qpart, g2);
  k_q<<<dim3(R_), 64, 0, stream>>>(qpart, Wq, q_ws);
  k_attn<<<dim3(8, R_), 256, 0, stream>>>(q_ws, kv, apart);
  k_comb<<<dim3(R_), 64, 0, stream>>>(apart, osm_ws);
  k_out<<<dim3(8, R_), 256, 0, stream>>>(g2, osm_ws, Wo, bo, out);
}